// Round 1
// baseline (881.954 us; speedup 1.0000x reference)
//
#include <hip/hip_runtime.h>

// Problem constants (from reference)
#define FP8_MAX      240.0f
#define NUM_TOKENS   32768
#define NUM_BLOCKS   1024
#define BLOCK_SIZE   128
#define NUM_KV_HEADS 8
#define HEAD_DIM     128
#define ROW_ELEMS    (NUM_KV_HEADS * HEAD_DIM)   // 1024 floats per (block,offset) row
#define ROW_VEC4     (ROW_ELEMS / 4)             // 256 float4 per row
#define NUM_ROWS     (NUM_BLOCKS * BLOCK_SIZE)   // 131072 rows

// ---------------------------------------------------------------------------
// Kernel 1: init inverse map (slot -> token) to -1. 131072 ints = 32768 int4.
// ---------------------------------------------------------------------------
__global__ void kv_init_map(int4* __restrict__ map4) {
    int i = blockIdx.x * blockDim.x + threadIdx.x;   // 0 .. 32767
    map4[i] = make_int4(-1, -1, -1, -1);
}

// ---------------------------------------------------------------------------
// Kernel 2: scatter token ids into the map. Unique slots => no conflicts.
// ---------------------------------------------------------------------------
__global__ void kv_scatter_map(const int* __restrict__ block_indices,
                               const int* __restrict__ block_offset,
                               int* __restrict__ map) {
    int t = blockIdx.x * blockDim.x + threadIdx.x;   // 0 .. NUM_TOKENS-1
    map[block_indices[t] * BLOCK_SIZE + block_offset[t]] = t;
}

// ---------------------------------------------------------------------------
// Kernel 3: one block per (block,offset) row (1024 floats = 256 float4).
// If the row was written by a token: out = clip(input/s_in, +-240) * s_out
// Else:                              out = cache * s_out
// Branch is wave-uniform (all 256 threads share one map value).
// ---------------------------------------------------------------------------
__global__ void kv_write_out(const float4* __restrict__ input,
                             const float4* __restrict__ cache,
                             const int* __restrict__ map,
                             const float* __restrict__ s_in_p,
                             const float* __restrict__ s_out_p,
                             float4* __restrict__ out) {
    const int row = blockIdx.x;        // 0 .. NUM_ROWS-1
    const int j   = threadIdx.x;       // 0 .. 255
    const int t   = map[row];
    const float s_out = *s_out_p;

    float4 v;
    if (t >= 0) {
        const float s_in = *s_in_p;
        v = input[(size_t)t * ROW_VEC4 + j];
        v.x = fminf(fmaxf(v.x / s_in, -FP8_MAX), FP8_MAX) * s_out;
        v.y = fminf(fmaxf(v.y / s_in, -FP8_MAX), FP8_MAX) * s_out;
        v.z = fminf(fmaxf(v.z / s_in, -FP8_MAX), FP8_MAX) * s_out;
        v.w = fminf(fmaxf(v.w / s_in, -FP8_MAX), FP8_MAX) * s_out;
    } else {
        v = cache[(size_t)row * ROW_VEC4 + j];
        v.x *= s_out;
        v.y *= s_out;
        v.z *= s_out;
        v.w *= s_out;
    }
    out[(size_t)row * ROW_VEC4 + j] = v;
}

// ---------------------------------------------------------------------------
// Launch
// ---------------------------------------------------------------------------
extern "C" void kernel_launch(void* const* d_in, const int* in_sizes, int n_in,
                              void* d_out, int out_size, void* d_ws, size_t ws_size,
                              hipStream_t stream) {
    const float* input         = (const float*)d_in[0];  // (32768, 8, 128) fp32
    const float* cache         = (const float*)d_in[1];  // (1024, 128, 8, 128) fp32
    const int*   block_indices = (const int*)  d_in[2];  // (32768,)
    const int*   block_offset  = (const int*)  d_in[3];  // (32768,)
    const float* s_in          = (const float*)d_in[4];  // scalar
    const float* s_out         = (const float*)d_in[5];  // scalar
    float*       out           = (float*)      d_out;    // (1024, 128, 8, 128) fp32
    int*         map           = (int*)        d_ws;     // 131072 ints = 512 KB

    // 1) map[slot] = -1
    kv_init_map<<<(NUM_ROWS / 4) / 256, 256, 0, stream>>>((int4*)map);
    // 2) map[bi*128 + bo] = token
    kv_scatter_map<<<NUM_TOKENS / 256, 256, 0, stream>>>(block_indices, block_offset, map);
    // 3) single fused output pass
    kv_write_out<<<NUM_ROWS, 256, 0, stream>>>((const float4*)input,
                                               (const float4*)cache,
                                               map, s_in, s_out,
                                               (float4*)out);
}